// Round 16
// baseline (697.022 us; speedup 1.0000x reference)
//
#include <hip/hip_runtime.h>

#define NV 200000
#define NE 1600000
#define CD 128
#define NBUCK 3125            // NV/64 buckets of 64 rows
#define NBLK 128
#define CHUNK 12500           // NBLK*CHUNK = NE exactly

// ---- workspace layout (bytes) ----
#define Y_OFF      0UL           // y bf16-packed: NV*CD*2 = 51,200,000
#define CNT_OFF    51200000UL    // NBLK*NBUCK ints = 1,600,000
#define START_OFF  52812544UL    // NBUCK+1 ints
#define SCAT_OFF   52825088UL    // NE int2 = 12,800,000
#define ROWOFF_OFF 65625088UL    // NV+1 ints
#define SCAT2_OFF  66425344UL    // NE int2 = 12,800,000
#define BAR_OFF    79225344UL    // 4 barrier ints + 5 tile counters (64 B zeroed)

#define FUSED_BLOCKS 512
#define NTILES (NV / 16)         // 12500
// phase tile boundaries (phase k covers [B_k, B_{k+1}) via its own counter)
#define B0 0
#define B1 2400
#define B2 3000
#define B3 4600
#define B4 7200
#define B5 NTILES

typedef short  short8 __attribute__((ext_vector_type(8)));
typedef float  f32x4  __attribute__((ext_vector_type(4)));

__device__ __forceinline__ unsigned bf16pair(float a, float b) {
    unsigned ua = __float_as_uint(a);
    unsigned ub = __float_as_uint(b);
    ua += 0x7fffu + ((ua >> 16) & 1u);   // RNE
    ub += 0x7fffu + ((ub >> 16) & 1u);
    return (ua >> 16) | (ub & 0xffff0000u);
}

__device__ __forceinline__ short bf16of(float f) {
    __bf16 h = (__bf16)f;
    return __builtin_bit_cast(short, h);
}

// Grid barrier. All FUSED_BLOCKS resident by construction (512 blocks, 2/CU:
// 32 KB LDS, 8 waves, VGPR under launch_bounds(256,2)).
// Arrive = release RMW (emits L2 writeback at agent scope); spin = relaxed
// agent-scope LOAD (no RMW storm — the r11 mistake); threadfence after exit
// invalidates stale per-XCD L2 lines before the next phase reads.
__device__ __forceinline__ void gbar(int* c) {
    __syncthreads();
    if (threadIdx.x == 0) {
        __hip_atomic_fetch_add(c, 1, __ATOMIC_RELEASE, __HIP_MEMORY_SCOPE_AGENT);
        while (__hip_atomic_load(c, __ATOMIC_RELAXED, __HIP_MEMORY_SCOPE_AGENT) < FUSED_BLOCKS)
            __builtin_amdgcn_s_sleep(4);
    }
    __syncthreads();
    __threadfence();
}

// =============== Fused kernel: gemm + CSR build, 5 phases, wave-level stealing ===============
__global__ __launch_bounds__(256, 2) void fused(const float* __restrict__ x,
                                                const float* __restrict__ Wm,
                                                unsigned short* __restrict__ y,
                                                const int* __restrict__ rows,
                                                const int* __restrict__ cols,
                                                const float* __restrict__ vals,
                                                int* __restrict__ cnt,
                                                int* __restrict__ start,
                                                int2* __restrict__ scat,
                                                int* __restrict__ rowoff,
                                                int2* __restrict__ scat2,
                                                int* __restrict__ bar) {
    __shared__ __align__(16) char smem[32768];
    int* ctr = bar + 4;   // 5 per-phase tile counters

    const int t = threadIdx.x;
    const int bid = blockIdx.x;
    const int lane = t & 63;
    const int g = lane >> 4;

    short* Wlds = reinterpret_cast<short*>(smem);
    int* ibuf = reinterpret_cast<int*>(smem);

    // ---- stage W -> LDS (fp32->bf16, fragment-linear), hoist A into VGPRs ----
    {
        const float4* Wf4 = reinterpret_cast<const float4*>(Wm);
        uint4* L = reinterpret_cast<uint4*>(Wlds);
#pragma unroll
        for (int i = 0; i < 8; ++i) {
            int c = t + i * 256;
            int l = c & 63;
            int ks = (c >> 6) & 3;
            int tl = c >> 8;
            int row = 16 * tl + (l & 15);
            int j = ks * 4 + (l >> 4);
            float4 wa = Wf4[row * 32 + j * 2];
            float4 wb = Wf4[row * 32 + j * 2 + 1];
            uint4 u;
            u.x = bf16pair(wa.x, wa.y);
            u.y = bf16pair(wa.z, wa.w);
            u.z = bf16pair(wb.x, wb.y);
            u.w = bf16pair(wb.z, wb.w);
            L[c] = u;
        }
    }
    __syncthreads();

    short8 A[8][4];
    {
        const short8* L8 = reinterpret_cast<const short8*>(Wlds);
#pragma unroll
        for (int t8 = 0; t8 < 8; ++t8)
#pragma unroll
            for (int ks = 0; ks < 4; ++ks)
                A[t8][ks] = L8[(t8 * 4 + ks) * 64 + lane];
    }
    __syncthreads();   // Wlds dead; smem reusable by build phases

    char* yb = reinterpret_cast<char*>(y);
    auto do_tile = [&](int tile) {
        const int v0 = tile * 16;
        const int row = v0 + (lane & 15);
        const float4* xr = reinterpret_cast<const float4*>(x + (size_t)row * CD);
        float4 xf[8];
#pragma unroll
        for (int ks = 0; ks < 4; ++ks) {
            xf[2 * ks]     = xr[8 * ks + 2 * g];
            xf[2 * ks + 1] = xr[8 * ks + 2 * g + 1];
        }
        f32x4 acc[8];
#pragma unroll
        for (int t8 = 0; t8 < 8; ++t8) acc[t8] = (f32x4){0.f, 0.f, 0.f, 0.f};
#pragma unroll
        for (int ks = 0; ks < 4; ++ks) {
            short8 B;
            const float* f = reinterpret_cast<const float*>(&xf[2 * ks]);
#pragma unroll
            for (int j = 0; j < 8; ++j) B[j] = bf16of(f[j]);
#pragma unroll
            for (int t8 = 0; t8 < 8; ++t8)
                acc[t8] = __builtin_amdgcn_mfma_f32_16x16x32_bf16(A[t8][ks], B, acc[t8], 0, 0, 0);
        }
        const size_t rb = (size_t)(v0 + (lane & 15)) * 256;
#pragma unroll
        for (int t8 = 0; t8 < 8; ++t8) {
            ushort4 o;
            o.x = (unsigned short)bf16of(acc[t8][0]);
            o.y = (unsigned short)bf16of(acc[t8][1]);
            o.z = (unsigned short)bf16of(acc[t8][2]);
            o.w = (unsigned short)bf16of(acc[t8][3]);
            *reinterpret_cast<ushort4*>(yb + rb + t8 * 32 + g * 8) = o;
        }
    };
    // WAVE-level work stealing: lane 0 pulls a tile index, broadcast to the
    // wave (MFMA is a per-wave collective — tile MUST be wave-uniform; the
    // per-thread steal was r15's NaN bug).
    auto gemm_phase = [&](int k, int lo, int hi) {
        for (;;) {
            int idx = 0;
            if (lane == 0) idx = atomicAdd(&ctr[k], 1);
            idx = __shfl(idx, 0);
            int tile = lo + idx;
            if (tile >= hi) break;
            do_tile(tile);
        }
    };

    // ---------- P0: pc (blocks 0..127) | gemm [B0,B1) ----------
    if (bid < NBLK) {
        int* hist = ibuf;
        for (int i = t; i < NBUCK; i += 256) hist[i] = 0;
        __syncthreads();
        const int e0 = bid * CHUNK;
        for (int e = e0 + t; e < e0 + CHUNK; e += 256)
            atomicAdd(&hist[rows[e] >> 6], 1);
        __syncthreads();
        for (int i = t; i < NBUCK; i += 256)
            cnt[(size_t)bid * NBUCK + i] = hist[i];
        __syncthreads();
    }
    gemm_phase(0, B0, B1);
    gbar(bar + 0);

    // ---------- P1: ps (blocks 0..12) | gemm [B1,B2) ----------
    if (bid < 13) {
        int gi = bid * 256 + t;
        if (gi < NBUCK) {
            int running = 0;
            for (int blk = 0; blk < NBLK; ++blk) {
                int idx = blk * NBUCK + gi;
                int c = cnt[idx];
                cnt[idx] = running;
                running += c;
            }
            start[gi] = running;   // temporarily bucket totals
        }
    }
    gemm_phase(1, B1, B2);
    gbar(bar + 1);

    // ---------- P2: pt (block 0 scans totals in-place) | gemm [B2,B3) ----------
    if (bid == 0) {
        int* s = ibuf;
        if (t == 0) ibuf[256] = 0;   // carry slot
        __syncthreads();
        for (int c = 0; c < 13; ++c) {
            int idx = c * 256 + t;
            int v = (idx < NBUCK) ? start[idx] : 0;
            s[t] = v;
            __syncthreads();
            for (int d = 1; d < 256; d <<= 1) {
                int add = (t >= d) ? s[t - d] : 0;
                __syncthreads();
                s[t] += add;
                __syncthreads();
            }
            int carry = ibuf[256];
            if (idx < NBUCK) start[idx] = carry + s[t] - v;   // exclusive prefix
            __syncthreads();
            if (t == 255) ibuf[256] = carry + s[255];
            __syncthreads();
        }
        if (t == 0) start[NBUCK] = NE;
        __syncthreads();
    }
    gemm_phase(2, B2, B3);
    gbar(bar + 2);

    // ---------- P3: px (blocks 0..127) | gemm [B3,B4) ----------
    if (bid < NBLK) {
        int* cur = ibuf;
        for (int i = t; i < NBUCK; i += 256)
            cur[i] = start[i] + cnt[(size_t)bid * NBUCK + i];
        __syncthreads();
        const int e0 = bid * CHUNK;
        for (int e = e0 + t; e < e0 + CHUNK; e += 256) {
            int r = rows[e];
            int pos = atomicAdd(&cur[r >> 6], 1);
            scat[pos] = make_int2(cols[e] | ((r & 63) << 18), __float_as_int(vals[e]));
        }
        __syncthreads();
    }
    gemm_phase(3, B3, B4);
    gbar(bar + 3);

    // ---------- P4: drain gemm, then k_sort (all blocks) ----------
    gemm_phase(4, B4, B5);

    int* rc = ibuf;
    int* ri = ibuf + 64;
    int* cu = ibuf + 128;
    for (int b = bid; b < NBUCK; b += FUSED_BLOCKS) {
        const int s0 = start[b], s1 = start[b + 1];
        __syncthreads();
        if (t < 64) rc[t] = 0;
        __syncthreads();
        for (int e = s0 + t; e < s1; e += 256)
            atomicAdd(&rc[(scat[e].x >> 18) & 63], 1);
        __syncthreads();
        if (t < 64) ri[t] = rc[t];
        __syncthreads();
        for (int d = 1; d < 64; d <<= 1) {
            int add = 0;
            if (t < 64 && t >= d) add = ri[t - d];
            __syncthreads();
            if (t < 64) ri[t] += add;
            __syncthreads();
        }
        if (t < 64) {
            int excl = ri[t] - rc[t];
            cu[t] = excl;
            rowoff[b * 64 + t] = s0 + excl;
        }
        __syncthreads();
        for (int e = s0 + t; e < s1; e += 256) {
            int2 p = scat[e];
            int lr = (p.x >> 18) & 63;
            int pos = s0 + atomicAdd(&cu[lr], 1);
            scat2[pos] = p;
        }
    }
    if (bid == 0 && t == 0) rowoff[NV] = NE;
}

// ---------------- gather: 1 wave per row, quarter-split (16 lanes/edge, uint4) ----------------
// (round-9 proven: 83 us, pattern roofline per r12's falsified MALL-split test)
#define BFLO(u) __uint_as_float((u) << 16)
#define BFHI(u) __uint_as_float((u) & 0xffff0000u)

__global__ __launch_bounds__(256) void k_gather(const int* __restrict__ rowoff,
                                                const int2* __restrict__ scat2,
                                                const uint4* __restrict__ y4,
                                                const float* __restrict__ b,
                                                float* __restrict__ out) {
    const int wid = threadIdx.x >> 6;
    const int lane = threadIdx.x & 63;
    const int q = lane >> 4;
    const int sl = lane & 15;
    const int row = blockIdx.x * 4 + wid;

    const int s0 = rowoff[row];
    const int n = rowoff[row + 1] - s0;

    float4 accA, accB;
    if (q == 0) {
        accA = reinterpret_cast<const float4*>(b)[2 * sl];
        accB = reinterpret_cast<const float4*>(b)[2 * sl + 1];
    } else {
        accA = make_float4(0.f, 0.f, 0.f, 0.f);
        accB = make_float4(0.f, 0.f, 0.f, 0.f);
    }

    int k = q;
    for (; k + 4 < n; k += 8) {
        int2 pa = scat2[s0 + k];
        int2 pb = scat2[s0 + k + 4];
        uint4 ua = y4[(size_t)(pa.x & 0x3ffff) * 16 + sl];
        uint4 ub = y4[(size_t)(pb.x & 0x3ffff) * 16 + sl];
        float va = __int_as_float(pa.y), vb = __int_as_float(pb.y);
        accA.x += va * BFLO(ua.x) + vb * BFLO(ub.x);
        accA.y += va * BFHI(ua.x) + vb * BFHI(ub.x);
        accA.z += va * BFLO(ua.y) + vb * BFLO(ub.y);
        accA.w += va * BFHI(ua.y) + vb * BFHI(ub.y);
        accB.x += va * BFLO(ua.z) + vb * BFLO(ub.z);
        accB.y += va * BFHI(ua.z) + vb * BFHI(ub.z);
        accB.z += va * BFLO(ua.w) + vb * BFLO(ub.w);
        accB.w += va * BFHI(ua.w) + vb * BFHI(ub.w);
    }
    if (k < n) {
        int2 p = scat2[s0 + k];
        uint4 u = y4[(size_t)(p.x & 0x3ffff) * 16 + sl];
        float v = __int_as_float(p.y);
        accA.x += v * BFLO(u.x);
        accA.y += v * BFHI(u.x);
        accA.z += v * BFLO(u.y);
        accA.w += v * BFHI(u.y);
        accB.x += v * BFLO(u.z);
        accB.y += v * BFHI(u.z);
        accB.z += v * BFLO(u.w);
        accB.w += v * BFHI(u.w);
    }

    accA.x += __shfl_xor(accA.x, 16); accA.x += __shfl_xor(accA.x, 32);
    accA.y += __shfl_xor(accA.y, 16); accA.y += __shfl_xor(accA.y, 32);
    accA.z += __shfl_xor(accA.z, 16); accA.z += __shfl_xor(accA.z, 32);
    accA.w += __shfl_xor(accA.w, 16); accA.w += __shfl_xor(accA.w, 32);
    accB.x += __shfl_xor(accB.x, 16); accB.x += __shfl_xor(accB.x, 32);
    accB.y += __shfl_xor(accB.y, 16); accB.y += __shfl_xor(accB.y, 32);
    accB.z += __shfl_xor(accB.z, 16); accB.z += __shfl_xor(accB.z, 32);
    accB.w += __shfl_xor(accB.w, 16); accB.w += __shfl_xor(accB.w, 32);

    if (q == 0) {
        f32x4 sA = {accA.x, accA.y, accA.z, accA.w};
        f32x4 sB = {accB.x, accB.y, accB.z, accB.w};
        float* o = out + (size_t)row * CD + sl * 8;
        __builtin_nontemporal_store(sA, (f32x4*)o);
        __builtin_nontemporal_store(sB, (f32x4*)(o + 4));
    }
}

extern "C" void kernel_launch(void* const* d_in, const int* in_sizes, int n_in,
                              void* d_out, int out_size, void* d_ws, size_t ws_size,
                              hipStream_t stream) {
    const float* x    = (const float*)d_in[0];
    const int*   rows = (const int*)d_in[1];
    const int*   cols = (const int*)d_in[2];
    const float* vals = (const float*)d_in[3];
    const float* Wm   = (const float*)d_in[4];
    const float* b    = (const float*)d_in[5];
    float* out = (float*)d_out;

    char* ws = (char*)d_ws;
    unsigned short* y  = (unsigned short*)(ws + Y_OFF);
    int* cnt           = (int*)(ws + CNT_OFF);
    int* start         = (int*)(ws + START_OFF);
    int2* scat         = (int2*)(ws + SCAT_OFF);
    int* rowoff        = (int*)(ws + ROWOFF_OFF);
    int2* scat2        = (int2*)(ws + SCAT2_OFF);
    int* bar           = (int*)(ws + BAR_OFF);

    hipMemsetAsync(bar, 0, 64, stream);   // 4 barrier ints + 5 tile counters
    fused<<<FUSED_BLOCKS, 256, 0, stream>>>(x, Wm, y, rows, cols, vals,
                                            cnt, start, scat, rowoff, scat2, bar);
    k_gather<<<NV / 4, 256, 0, stream>>>(rowoff, scat2, (const uint4*)y, b, out);
}

// Round 17
// 182.114 us; speedup vs baseline: 3.8274x; 3.8274x over previous
//
#include <hip/hip_runtime.h>

#define NV 200000
#define NE 1600000
#define CD 128
#define NBUCK 3125            // NV/64 buckets of 64 rows
#define NBLK 64
#define CHUNK 25600           // NBLK*CHUNK = 1,638,400 >= NE

// ---- workspace layout (bytes) ----
#define Y_OFF      0UL           // y bf16-packed: NV*CD*2 = 51,200,000
#define CNT_OFF    51232768UL    // NBLK*NBUCK ints = 800,000
#define TOT_OFF    52032768UL    // NBUCK ints
#define START_OFF  52045312UL    // NBUCK+1 ints
#define SCAT_OFF   52058112UL    // NE int2 = 12,800,000
#define ROWOFF_OFF 64858112UL    // NV+1 ints
#define SCAT2_OFF  65658368UL    // NE int2 = 12,800,000 (end ~78.5 MB)

typedef short  short8 __attribute__((ext_vector_type(8)));
typedef float  f32x4  __attribute__((ext_vector_type(4)));

__device__ __forceinline__ unsigned bf16pair(float a, float b) {
    unsigned ua = __float_as_uint(a);
    unsigned ub = __float_as_uint(b);
    ua += 0x7fffu + ((ua >> 16) & 1u);   // RNE
    ub += 0x7fffu + ((ub >> 16) & 1u);
    return (ua >> 16) | (ub & 0xffff0000u);
}

__device__ __forceinline__ short bf16of(float f) {
    __bf16 h = (__bf16)f;
    return __builtin_bit_cast(short, h);
}

// ---------------- Fused Kernel 1: [pc histogram | gemm y=x@W^T via MFMA] ----------------
// Blocks 0..63: pc histogram. Blocks 64..575: gemm.
// NEW: all global x-loads / y-stores are contiguous 1KB wave transactions,
// staged through per-wave padded LDS tiles (de-fragmentation of TA requests —
// the direct fragment loads touched 64 scattered 16B segments per instruction).
#define PC_BLOCKS 64
#define GEMM_BLOCKS 512
#define GEMM_WAVES (GEMM_BLOCKS * 4)
#define NTILES (NV / 16)

// per-wave X tile: 16 rows x 33 float4 (pad f4 pitch 33 -> conflict-free b128)
#define XPITCH 33
#define XW_BYTES (16 * XPITCH * 16)    // 8448
// Y tile reuses the X buffer: 16 rows x 68 words (pitch 68 -> conflict-free)
#define YPITCH_W 68

__global__ __launch_bounds__(256, 2) void gemm_pc(const float* __restrict__ x,
                                                  const float* __restrict__ Wm,
                                                  unsigned short* __restrict__ y,
                                                  const int* __restrict__ rows,
                                                  int* __restrict__ cnt) {
    __shared__ __align__(16) char smem[32768 + 4 * XW_BYTES];   // 66,560 B
    const int t = threadIdx.x;

    if (blockIdx.x < PC_BLOCKS) {
        int* hist = reinterpret_cast<int*>(smem);
        const int blk = blockIdx.x;
        for (int i = t; i < NBUCK; i += 256) hist[i] = 0;
        __syncthreads();
        const int e0 = blk * CHUNK;
        const int e1 = min(NE, e0 + CHUNK);
        for (int e = e0 + t; e < e1; e += 256)
            atomicAdd(&hist[rows[e] >> 6], 1);
        __syncthreads();
        for (int i = t; i < NBUCK; i += 256)
            cnt[(size_t)blk * NBUCK + i] = hist[i];
        return;
    }

    short* Wlds = reinterpret_cast<short*>(smem);
    const int lane = t & 63;
    const int w = t >> 6;
    const int g = lane >> 4;
    const int lrow = lane & 15;

    // stage W -> LDS (fp32->bf16, fragment-linear)
    {
        const float4* Wf4 = reinterpret_cast<const float4*>(Wm);
        uint4* L = reinterpret_cast<uint4*>(Wlds);
#pragma unroll
        for (int i = 0; i < 8; ++i) {
            int c = t + i * 256;
            int l = c & 63;
            int ks = (c >> 6) & 3;
            int tl = c >> 8;
            int row = 16 * tl + (l & 15);
            int j = ks * 4 + (l >> 4);
            float4 wa = Wf4[row * 32 + j * 2];
            float4 wb = Wf4[row * 32 + j * 2 + 1];
            uint4 u;
            u.x = bf16pair(wa.x, wa.y);
            u.y = bf16pair(wa.z, wa.w);
            u.z = bf16pair(wb.x, wb.y);
            u.w = bf16pair(wb.z, wb.w);
            L[c] = u;
        }
    }
    __syncthreads();

    short8 A[8][4];
    {
        const short8* L8 = reinterpret_cast<const short8*>(Wlds);
#pragma unroll
        for (int t8 = 0; t8 < 8; ++t8)
#pragma unroll
            for (int ks = 0; ks < 4; ++ks)
                A[t8][ks] = L8[(t8 * 4 + ks) * 64 + lane];
    }
    __syncthreads();

    // per-wave LDS tile (X, later reused as Y staging)
    char* xw = smem + 32768 + w * XW_BYTES;
    float4* Xs4 = reinterpret_cast<float4*>(xw);
    uint2*  Ys2 = reinterpret_cast<uint2*>(xw);
    uint4*  Ys4 = reinterpret_cast<uint4*>(xw);

    const int wgid = (blockIdx.x - PC_BLOCKS) * 4 + w;
    const float4* xg4 = reinterpret_cast<const float4*>(x);
    uint4* yg4 = reinterpret_cast<uint4*>(y);

    for (int tile = wgid; tile < NTILES; tile += GEMM_WAVES) {
        const int v0 = tile * 16;

        // ---- coalesced load: 8 x 1KB contiguous, then padded LDS write ----
        float4 xr4[8];
#pragma unroll
        for (int i = 0; i < 8; ++i) xr4[i] = xg4[(size_t)v0 * 32 + i * 64 + lane];
#pragma unroll
        for (int i = 0; i < 8; ++i) {
            int idx = i * 64 + lane;
            Xs4[(idx >> 5) * XPITCH + (idx & 31)] = xr4[i];
        }

        // ---- fragment reads from LDS + MFMA ----
        f32x4 acc[8];
#pragma unroll
        for (int t8 = 0; t8 < 8; ++t8) acc[t8] = (f32x4){0.f, 0.f, 0.f, 0.f};
#pragma unroll
        for (int ks = 0; ks < 4; ++ks) {
            float4 fa = Xs4[lrow * XPITCH + 8 * ks + 2 * g];
            float4 fb = Xs4[lrow * XPITCH + 8 * ks + 2 * g + 1];
            short8 B;
            B[0] = bf16of(fa.x); B[1] = bf16of(fa.y);
            B[2] = bf16of(fa.z); B[3] = bf16of(fa.w);
            B[4] = bf16of(fb.x); B[5] = bf16of(fb.y);
            B[6] = bf16of(fb.z); B[7] = bf16of(fb.w);
#pragma unroll
            for (int t8 = 0; t8 < 8; ++t8)
                acc[t8] = __builtin_amdgcn_mfma_f32_16x16x32_bf16(A[t8][ks], B, acc[t8], 0, 0, 0);
        }

        // ---- pack + stage to LDS Y tile (reuses X buffer; X is dead) ----
#pragma unroll
        for (int t8 = 0; t8 < 8; ++t8) {
            uint2 o;
            o.x = bf16pair(acc[t8][0], acc[t8][1]);
            o.y = bf16pair(acc[t8][2], acc[t8][3]);
            Ys2[lrow * (YPITCH_W / 2) + 4 * t8 + g] = o;
        }

        // ---- coalesced store: 4 x 1KB contiguous ----
#pragma unroll
        for (int i = 0; i < 4; ++i) {
            int idx = i * 64 + lane;
            int r = idx >> 4, c4 = idx & 15;
            yg4[(size_t)(v0 + r) * 16 + c4] = Ys4[r * (YPITCH_W / 4) + c4];
        }
    }
}

// ---------------- ps: cross-block exclusive prefix per bucket (in-place) ----------------
__global__ __launch_bounds__(256) void ps(int* __restrict__ cnt,
                                          int* __restrict__ tot) {
    int g = blockIdx.x * 256 + threadIdx.x;
    if (g >= NBUCK) return;
    int running = 0;
    for (int blk = 0; blk < NBLK; ++blk) {
        int idx = blk * NBUCK + g;
        int c = cnt[idx];
        cnt[idx] = running;       // rel[blk][bk]
        running += c;
    }
    tot[g] = running;
}

// ---------------- pt: scan bucket totals -> start[0..NBUCK] ----------------
__global__ __launch_bounds__(1024) void pt(const int* __restrict__ tot,
                                           int* __restrict__ start) {
    __shared__ int s[1024];
    const int t = threadIdx.x;
    if (t == 0) start[NBUCK] = NE;
    int carry = 0;
    for (int c = 0; c < 4; ++c) {
        int idx = c * 1024 + t;
        int v = (idx < NBUCK) ? tot[idx] : 0;
        s[t] = v;
        __syncthreads();
        for (int d = 1; d < 1024; d <<= 1) {
            int add = (t >= d) ? s[t - d] : 0;
            __syncthreads();
            s[t] += add;
            __syncthreads();
        }
        if (idx < NBUCK) start[idx] = carry + s[t] - v;
        carry += s[1023];
        __syncthreads();
    }
}

// ---------------- px: scatter edges into bucket order (block-owned runs) ----------------
__global__ __launch_bounds__(1024) void px(const int* __restrict__ rows,
                                           const int* __restrict__ cols,
                                           const float* __restrict__ vals,
                                           const int* __restrict__ cnt,
                                           const int* __restrict__ start,
                                           int2* __restrict__ scat) {
    __shared__ int cur[NBUCK];
    const int t = threadIdx.x;
    for (int i = t; i < NBUCK; i += 1024)
        cur[i] = start[i] + cnt[(size_t)blockIdx.x * NBUCK + i];
    __syncthreads();
    const int e0 = blockIdx.x * CHUNK;
    const int e1 = min(NE, e0 + CHUNK);
    for (int e = e0 + t; e < e1; e += 1024) {
        int r = rows[e];
        int pos = atomicAdd(&cur[r >> 6], 1);
        scat[pos] = make_int2(cols[e] | ((r & 63) << 18), __float_as_int(vals[e]));
    }
}

// ---------------- k_sort: within-bucket counting sort by local row ----------------
__global__ __launch_bounds__(256) void k_sort(const int* __restrict__ start,
                                              const int2* __restrict__ scat,
                                              int2* __restrict__ scat2,
                                              int* __restrict__ rowoff) {
    __shared__ int rcnt[64], rinc[64], cur[64];
    const int t = threadIdx.x;
    const int b = blockIdx.x;
    const int s0 = start[b], s1 = start[b + 1];

    if (t < 64) rcnt[t] = 0;
    __syncthreads();
    for (int e = s0 + t; e < s1; e += 256)
        atomicAdd(&rcnt[(scat[e].x >> 18) & 63], 1);
    __syncthreads();
    if (t < 64) rinc[t] = rcnt[t];
    __syncthreads();
    for (int d = 1; d < 64; d <<= 1) {
        int add = 0;
        if (t < 64 && t >= d) add = rinc[t - d];
        __syncthreads();
        if (t < 64) rinc[t] += add;
        __syncthreads();
    }
    if (t < 64) {
        int excl = rinc[t] - rcnt[t];
        cur[t] = excl;
        rowoff[b * 64 + t] = s0 + excl;
    }
    if (b == NBUCK - 1 && t == 0) rowoff[NV] = NE;
    __syncthreads();
    for (int e = s0 + t; e < s1; e += 256) {
        int2 p = scat[e];            // L1/L2-hot re-read
        int lr = (p.x >> 18) & 63;
        int pos = s0 + atomicAdd(&cur[lr], 1);
        scat2[pos] = p;
    }
}

// ---------------- gather: 1 wave per row, quarter-split (16 lanes/edge, uint4) ----------------
// (round-9 proven: 83 us, pattern roofline per r12's falsified MALL-split test)
#define BFLO(u) __uint_as_float((u) << 16)
#define BFHI(u) __uint_as_float((u) & 0xffff0000u)

__global__ __launch_bounds__(256) void k_gather(const int* __restrict__ rowoff,
                                                const int2* __restrict__ scat2,
                                                const uint4* __restrict__ y4,
                                                const float* __restrict__ b,
                                                float* __restrict__ out) {
    const int wid = threadIdx.x >> 6;
    const int lane = threadIdx.x & 63;
    const int q = lane >> 4;
    const int sl = lane & 15;
    const int row = blockIdx.x * 4 + wid;

    const int s0 = rowoff[row];
    const int n = rowoff[row + 1] - s0;

    float4 accA, accB;
    if (q == 0) {
        accA = reinterpret_cast<const float4*>(b)[2 * sl];
        accB = reinterpret_cast<const float4*>(b)[2 * sl + 1];
    } else {
        accA = make_float4(0.f, 0.f, 0.f, 0.f);
        accB = make_float4(0.f, 0.f, 0.f, 0.f);
    }

    int k = q;
    for (; k + 4 < n; k += 8) {
        int2 pa = scat2[s0 + k];
        int2 pb = scat2[s0 + k + 4];
        uint4 ua = y4[(size_t)(pa.x & 0x3ffff) * 16 + sl];
        uint4 ub = y4[(size_t)(pb.x & 0x3ffff) * 16 + sl];
        float va = __int_as_float(pa.y), vb = __int_as_float(pb.y);
        accA.x += va * BFLO(ua.x) + vb * BFLO(ub.x);
        accA.y += va * BFHI(ua.x) + vb * BFHI(ub.x);
        accA.z += va * BFLO(ua.y) + vb * BFLO(ub.y);
        accA.w += va * BFHI(ua.y) + vb * BFHI(ub.y);
        accB.x += va * BFLO(ua.z) + vb * BFLO(ub.z);
        accB.y += va * BFHI(ua.z) + vb * BFHI(ub.z);
        accB.z += va * BFLO(ua.w) + vb * BFLO(ub.w);
        accB.w += va * BFHI(ua.w) + vb * BFHI(ub.w);
    }
    if (k < n) {
        int2 p = scat2[s0 + k];
        uint4 u = y4[(size_t)(p.x & 0x3ffff) * 16 + sl];
        float v = __int_as_float(p.y);
        accA.x += v * BFLO(u.x);
        accA.y += v * BFHI(u.x);
        accA.z += v * BFLO(u.y);
        accA.w += v * BFHI(u.y);
        accB.x += v * BFLO(u.z);
        accB.y += v * BFHI(u.z);
        accB.z += v * BFLO(u.w);
        accB.w += v * BFHI(u.w);
    }

    accA.x += __shfl_xor(accA.x, 16); accA.x += __shfl_xor(accA.x, 32);
    accA.y += __shfl_xor(accA.y, 16); accA.y += __shfl_xor(accA.y, 32);
    accA.z += __shfl_xor(accA.z, 16); accA.z += __shfl_xor(accA.z, 32);
    accA.w += __shfl_xor(accA.w, 16); accA.w += __shfl_xor(accA.w, 32);
    accB.x += __shfl_xor(accB.x, 16); accB.x += __shfl_xor(accB.x, 32);
    accB.y += __shfl_xor(accB.y, 16); accB.y += __shfl_xor(accB.y, 32);
    accB.z += __shfl_xor(accB.z, 16); accB.z += __shfl_xor(accB.z, 32);
    accB.w += __shfl_xor(accB.w, 16); accB.w += __shfl_xor(accB.w, 32);

    if (q == 0) {
        f32x4 sA = {accA.x, accA.y, accA.z, accA.w};
        f32x4 sB = {accB.x, accB.y, accB.z, accB.w};
        float* o = out + (size_t)row * CD + sl * 8;
        __builtin_nontemporal_store(sA, (f32x4*)o);
        __builtin_nontemporal_store(sB, (f32x4*)(o + 4));
    }
}

extern "C" void kernel_launch(void* const* d_in, const int* in_sizes, int n_in,
                              void* d_out, int out_size, void* d_ws, size_t ws_size,
                              hipStream_t stream) {
    const float* x    = (const float*)d_in[0];
    const int*   rows = (const int*)d_in[1];
    const int*   cols = (const int*)d_in[2];
    const float* vals = (const float*)d_in[3];
    const float* Wm   = (const float*)d_in[4];
    const float* b    = (const float*)d_in[5];
    float* out = (float*)d_out;

    char* ws = (char*)d_ws;
    unsigned short* y  = (unsigned short*)(ws + Y_OFF);
    int* cnt           = (int*)(ws + CNT_OFF);
    int* tot           = (int*)(ws + TOT_OFF);
    int* start         = (int*)(ws + START_OFF);
    int2* scat         = (int2*)(ws + SCAT_OFF);
    int* rowoff        = (int*)(ws + ROWOFF_OFF);
    int2* scat2        = (int2*)(ws + SCAT2_OFF);

    gemm_pc<<<PC_BLOCKS + GEMM_BLOCKS, 256, 0, stream>>>(x, Wm, y, rows, cnt);
    ps<<<(NBUCK + 255) / 256, 256, 0, stream>>>(cnt, tot);
    pt<<<1, 1024, 0, stream>>>(tot, start);
    px<<<NBLK, 1024, 0, stream>>>(rows, cols, vals, cnt, start, scat);
    k_sort<<<NBUCK, 256, 0, stream>>>(start, scat, scat2, rowoff);
    k_gather<<<NV / 4, 256, 0, stream>>>(rowoff, scat2, (const uint4*)y, b, out);
}